// Round 15
// baseline (155.237 us; speedup 1.0000x reference)
//
#include <hip/hip_runtime.h>
#include <cfloat>
#include <cmath>

#define M     16384
#define K     4096
#define E     64
#define TOPK  8
#define GAP_THRESH 3e-4f

#define SPLIT 4                 // K-split (gate)
#define KPS   (K / SPLIT)       // 1024 k per wave
#define NCH   (KPS / 32)        // 32 chunks of k32
#define FIXR  2                 // rows per fix block

typedef __attribute__((ext_vector_type(8))) short bf16x8;
typedef __attribute__((ext_vector_type(4))) float f32x4;

// ws layout: [WdT 2MB][Whf 512KB][Wlf 512KB][count 256B][list 64KB][part 16MB]

__device__ __forceinline__ short f2bf(float f) {           // RNE fp32->bf16
    unsigned u = __builtin_bit_cast(unsigned, f);
    u += 0x7FFFu + ((u >> 16) & 1u);
    return (short)(u >> 16);
}
__device__ __forceinline__ float bf2f(short h) {           // exact widen
    unsigned u = ((unsigned)(unsigned short)h) << 16;
    return __builtin_bit_cast(float, u);
}

// ---------------------------------------------------------------------------
// prep (proven r14): Whf/Wlf in MFMA fragment order; WdT[k][e] fp64 written
// coalesced; zero flag counter.
// ---------------------------------------------------------------------------
__global__ __launch_bounds__(256) void prep_kernel(const float* __restrict__ W,
                                                   short* __restrict__ Whf,
                                                   short* __restrict__ Wlf,
                                                   double* __restrict__ WdT,
                                                   int* __restrict__ count) {
    int t = blockIdx.x * 256 + threadIdx.x;   // t = e*4096 + k
    float w = W[t];
    short h = f2bf(w);
    short lo = f2bf(w - bf2f(h));
    int e = t >> 12, k = t & 4095;
    int gc = k >> 5, kk = k & 31;
    size_t fidx = (((size_t)gc * 4 + (e >> 4)) * 64 + (kk >> 3) * 16 + (e & 15)) * 8
                  + (kk & 7);
    Whf[fidx] = h;
    Wlf[fidx] = lo;
    // coalesced WdT write: reinterpret t as k-major (t = k2*64 + e2)
    int k2 = t >> 6, e2 = t & 63;
    WdT[t] = (double)W[(size_t)e2 * K + k2];
    if (t == 0) *count = 0;
}

// ---------------------------------------------------------------------------
// MFMA gate (proven r12-r14): LDS-free, explicit 2-deep register pipeline,
// fragment-ordered W, 16 waves/CU, no barriers.
// ---------------------------------------------------------------------------
struct XW {
    float4 xa, xb;
    bf16x8 h0, h1, h2, h3, l0, l1, l2, l3;
};

__device__ __forceinline__ void load_set(XW& s, const float* gx,
                                         const short* ph, const short* pl, int cc) {
    const int ko = cc * 32;
    s.xa = *reinterpret_cast<const float4*>(gx + ko);
    s.xb = *reinterpret_cast<const float4*>(gx + ko + 4);
    const short* bh = ph + (size_t)cc * 2048;
    const short* bl = pl + (size_t)cc * 2048;
    s.h0 = *reinterpret_cast<const bf16x8*>(bh);
    s.h1 = *reinterpret_cast<const bf16x8*>(bh + 512);
    s.h2 = *reinterpret_cast<const bf16x8*>(bh + 1024);
    s.h3 = *reinterpret_cast<const bf16x8*>(bh + 1536);
    s.l0 = *reinterpret_cast<const bf16x8*>(bl);
    s.l1 = *reinterpret_cast<const bf16x8*>(bl + 512);
    s.l2 = *reinterpret_cast<const bf16x8*>(bl + 1024);
    s.l3 = *reinterpret_cast<const bf16x8*>(bl + 1536);
}

__device__ __forceinline__ void compute_set(const XW& s, f32x4 acc[4]) {
    float vv[8] = {s.xa.x, s.xa.y, s.xa.z, s.xa.w, s.xb.x, s.xb.y, s.xb.z, s.xb.w};
    bf16x8 ah, al;
#pragma unroll
    for (int j = 0; j < 8; ++j) {
        short hh = f2bf(vv[j]);
        ah[j] = hh;
        al[j] = f2bf(vv[j] - bf2f(hh));
    }
    acc[0] = __builtin_amdgcn_mfma_f32_16x16x32_bf16(ah, s.h0, acc[0], 0, 0, 0);
    acc[0] = __builtin_amdgcn_mfma_f32_16x16x32_bf16(ah, s.l0, acc[0], 0, 0, 0);
    acc[0] = __builtin_amdgcn_mfma_f32_16x16x32_bf16(al, s.h0, acc[0], 0, 0, 0);
    acc[1] = __builtin_amdgcn_mfma_f32_16x16x32_bf16(ah, s.h1, acc[1], 0, 0, 0);
    acc[1] = __builtin_amdgcn_mfma_f32_16x16x32_bf16(ah, s.l1, acc[1], 0, 0, 0);
    acc[1] = __builtin_amdgcn_mfma_f32_16x16x32_bf16(al, s.h1, acc[1], 0, 0, 0);
    acc[2] = __builtin_amdgcn_mfma_f32_16x16x32_bf16(ah, s.h2, acc[2], 0, 0, 0);
    acc[2] = __builtin_amdgcn_mfma_f32_16x16x32_bf16(ah, s.l2, acc[2], 0, 0, 0);
    acc[2] = __builtin_amdgcn_mfma_f32_16x16x32_bf16(al, s.h2, acc[2], 0, 0, 0);
    acc[3] = __builtin_amdgcn_mfma_f32_16x16x32_bf16(ah, s.h3, acc[3], 0, 0, 0);
    acc[3] = __builtin_amdgcn_mfma_f32_16x16x32_bf16(ah, s.l3, acc[3], 0, 0, 0);
    acc[3] = __builtin_amdgcn_mfma_f32_16x16x32_bf16(al, s.h3, acc[3], 0, 0, 0);
}

__global__ __launch_bounds__(256) void gate_kernel(
    const float* __restrict__ x,
    const short* __restrict__ Whf,
    const short* __restrict__ Wlf,
    float* __restrict__ part)
{
    const int t  = threadIdx.x;
    const int l  = t & 63;
    const int wv = t >> 6;
    const int h    = blockIdx.x & (SPLIT - 1);        // 4 waves share k-slice
    const int row0 = (blockIdx.x >> 2) * 64 + wv * 16;
    const int k0   = h * KPS;

    const int kg   = l >> 4;                          // 0..3 k-granule
    const int xrow = row0 + (l & 15);

    const float* gx = x + (size_t)xrow * K + k0 + kg * 8;
    const short* ph = Whf + ((size_t)(k0 >> 5) * 4) * 512 + (size_t)l * 8;
    const short* pl = Wlf + ((size_t)(k0 >> 5) * 4) * 512 + (size_t)l * 8;

    f32x4 acc[4] = {{0,0,0,0},{0,0,0,0},{0,0,0,0},{0,0,0,0}};

    XW A, B;
    load_set(A, gx, ph, pl, 0);
    for (int c = 0; c < NCH; c += 2) {
        load_set(B, gx, ph, pl, c + 1);
        compute_set(A, acc);
        if (c + 2 < NCH) load_set(A, gx, ph, pl, c + 2);
        compute_set(B, acc);
    }

    // D layout (verified r10-r14): row = (l>>4)*4 + r, col = l&15
#pragma unroll
    for (int et = 0; et < 4; ++et)
#pragma unroll
        for (int r = 0; r < 4; ++r)
            part[((size_t)h * M + row0 + (l >> 4) * 4 + r) * E + et * 16 + (l & 15)]
                = acc[et][r];
}

// ---------------------------------------------------------------------------
// Reduce + top-9 + sparse softmax + ambiguity flag (proven rounds 3-14).
// ---------------------------------------------------------------------------
__global__ __launch_bounds__(256) void reduce_kernel(
    const float* __restrict__ part,
    const float* __restrict__ b,
    float* __restrict__ outp,
    float* __restrict__ outi,
    int*   __restrict__ count,
    int*   __restrict__ list)
{
    const int lane = threadIdx.x & 63;
    const int w    = threadIdx.x >> 6;
    const int row  = blockIdx.x * 4 + w;

    float orig = b[lane];
#pragma unroll
    for (int hh = 0; hh < SPLIT; ++hh)
        orig += part[((size_t)hh * M + row) * E + lane];

    float cur = orig;
    float vals[9];
    float myidxf = 0.0f;
    bool  sel = false;

#pragma unroll
    for (int i = 0; i < 9; ++i) {
        float m = cur;
#pragma unroll
        for (int off = 32; off > 0; off >>= 1)
            m = fmaxf(m, __shfl_xor(m, off, 64));
        unsigned long long msk = __ballot(cur == m);
        int il = __ffsll((long long)msk) - 1;
        vals[i] = m;
        if (lane == il) { cur = -FLT_MAX; if (i < TOPK) sel = true; }
        if (i < TOPK && lane == i) myidxf = (float)il;
    }

    float ssum = 0.0f;
#pragma unroll
    for (int i = 0; i < TOPK; ++i) ssum += expf(vals[i] - vals[0]);
    float p = sel ? (expf(orig - vals[0]) / ssum) : 0.0f;

    outp[(size_t)row * E + lane] = p;
    if (lane < TOPK) outi[(size_t)row * TOPK + lane] = myidxf;

    float mingap = FLT_MAX;
#pragma unroll
    for (int i = 0; i < 8; ++i) mingap = fminf(mingap, vals[i] - vals[i + 1]);
    if (lane == 0 && mingap < GAP_THRESH) {
        int pos = atomicAdd(count, 1);
        if (pos < M) list[pos] = row;
    }
}

// ---------------------------------------------------------------------------
// fp64 rescue, r15: BURST loads.  r12-r14 paid one full L2 latency per 4-k
// quad (403 cyc/iter measured r12); the 1-deep rotation prefetch only hid
// ~40 cyc.  Now: per 32-k burst, all 32 independent WdT loads are issued
// into a fully-unrolled static-indexed n[32] (registers, rule #20), then
// 64 fp64 FMAs consume them -- ONE latency exposure per 32 k (8x fewer).
// 512 thr = 8 waves x 512 k; 2 rows/block share each load; waves 0/1 run
// the proven ballot epilogues.
// ---------------------------------------------------------------------------
__global__ __launch_bounds__(512) void fix_kernel(
    const float*  __restrict__ x,
    const double* __restrict__ WdT,
    const float*  __restrict__ b,
    float* __restrict__ outp,
    float* __restrict__ outi,
    const int* __restrict__ count,
    const int* __restrict__ list)
{
    __shared__ float  xs[FIXR][K];        // 32 KB
    __shared__ double psum[8][FIXR][E];   //  8 KB
    const int t   = threadIdx.x;
    const int l   = t & 63;
    const int wv  = t >> 6;               // 0..7
    const int cnt = *count;

    for (int base = blockIdx.x * FIXR; base < cnt; base += gridDim.x * FIXR) {
        int row[FIXR];
#pragma unroll
        for (int r = 0; r < FIXR; ++r)
            row[r] = list[min(base + r, cnt - 1)];

        // stage both rows: 2048 float4 over 512 thr = 4 each, coalesced
#pragma unroll
        for (int j = 0; j < 4; ++j) {
            const int i4 = j * 512 + t;           // 0..2047
            const int rr = i4 >> 10;              // row 0/1
            const int p4 = i4 & 1023;
            reinterpret_cast<float4*>(xs[rr])[p4] =
                reinterpret_cast<const float4*>(x + (size_t)row[rr] * K)[p4];
        }
        __syncthreads();

        const int k0 = wv << 9;                   // 512 k per wave
        const double* wp = WdT + (size_t)k0 * E + l;

        double a00 = 0.0, a01 = 0.0, a02 = 0.0, a03 = 0.0;
        double a10 = 0.0, a11 = 0.0, a12 = 0.0, a13 = 0.0;

        for (int kb = 0; kb < 512; kb += 32) {    // 16 bursts
            double n[32];
#pragma unroll
            for (int q = 0; q < 32; ++q)          // 32 independent loads in flight
                n[q] = wp[(size_t)(kb + q) * E];
#pragma unroll
            for (int q = 0; q < 32; q += 4) {
                float4 xv0 = *reinterpret_cast<const float4*>(xs[0] + k0 + kb + q);
                float4 xv1 = *reinterpret_cast<const float4*>(xs[1] + k0 + kb + q);
                a00 = fma((double)xv0.x, n[q + 0], a00);
                a01 = fma((double)xv0.y, n[q + 1], a01);
                a02 = fma((double)xv0.z, n[q + 2], a02);
                a03 = fma((double)xv0.w, n[q + 3], a03);
                a10 = fma((double)xv1.x, n[q + 0], a10);
                a11 = fma((double)xv1.y, n[q + 1], a11);
                a12 = fma((double)xv1.z, n[q + 2], a12);
                a13 = fma((double)xv1.w, n[q + 3], a13);
            }
        }
        psum[wv][0][l] = (a00 + a01) + (a02 + a03);
        psum[wv][1][l] = (a10 + a11) + (a12 + a13);
        __syncthreads();

        if (wv < FIXR) {
            const int r   = wv;
            const int idx = base + r;
            double orig = (double)b[l];
#pragma unroll
            for (int w = 0; w < 8; ++w) orig += psum[w][r][l];
            double cur = orig;

            double vals[TOPK];
            float  myidxf = 0.0f;
            bool   sel = false;

#pragma unroll
            for (int tt = 0; tt < TOPK; ++tt) {
                double m = cur;
#pragma unroll
                for (int off = 32; off > 0; off >>= 1) {
                    double o = __shfl_xor(m, off, 64);
                    m = fmax(m, o);
                }
                unsigned long long msk = __ballot(cur == m);
                int il = __ffsll((long long)msk) - 1;
                vals[tt] = m;
                if (l == il) { cur = -DBL_MAX; sel = true; }
                if (l == tt)  myidxf = (float)il;
            }

            double ssum = 0.0;
#pragma unroll
            for (int tt = 0; tt < TOPK; ++tt) ssum += exp(vals[tt] - vals[0]);
            float p = sel ? (float)(exp(orig - vals[0]) / ssum) : 0.0f;

            if (idx < cnt) {
                const int rw = row[r];
                outp[(size_t)rw * E + l] = p;
                if (l < TOPK) outi[(size_t)rw * TOPK + l] = myidxf;
            }
        }
        __syncthreads();   // xs/psum reused next pass
    }
}

// ---------------------------------------------------------------------------
// Fallback (tiny ws): per-thread-row full fp64 from f32 W.  Correct, slow.
// ---------------------------------------------------------------------------
__global__ __launch_bounds__(64) void fallback_kernel(
    const float* __restrict__ x,
    const float* __restrict__ W,
    const float* __restrict__ b,
    float* __restrict__ outp,
    float* __restrict__ outi)
{
    const int row = blockIdx.x * 64 + threadIdx.x;
    double lg[64];
#pragma unroll
    for (int e = 0; e < 64; ++e) lg[e] = (double)b[e];
    const float* xr = x + (size_t)row * K;
    for (int k = 0; k < K; k += 4) {
        float4 xa = *reinterpret_cast<const float4*>(xr + k);
        double xd[4] = {(double)xa.x, (double)xa.y, (double)xa.z, (double)xa.w};
#pragma unroll
        for (int e = 0; e < 64; ++e) {
            const float* wp = W + (size_t)e * K + k;
            double a = lg[e];
#pragma unroll
            for (int j = 0; j < 4; ++j) a = fma(xd[j], (double)wp[j], a);
            lg[e] = a;
        }
    }
    unsigned long long selm = 0ull;
    double vals[TOPK]; int idx[TOPK];
#pragma unroll
    for (int i = 0; i < TOPK; ++i) {
        double m = -DBL_MAX; int mi = 0;
#pragma unroll
        for (int e = 0; e < 64; ++e) {
            bool gt = !((selm >> e) & 1ull) && (lg[e] > m);
            m = gt ? lg[e] : m; mi = gt ? e : mi;
        }
        vals[i] = m; idx[i] = mi; selm |= (1ull << mi);
    }
    double ssum = 0.0;
#pragma unroll
    for (int i = 0; i < TOPK; ++i) ssum += exp(vals[i] - vals[0]);
    double inv = 1.0 / ssum;
#pragma unroll
    for (int e = 0; e < 64; ++e)
        outp[(size_t)row * E + e] =
            ((selm >> e) & 1ull) ? (float)(exp(lg[e] - vals[0]) * inv) : 0.0f;
#pragma unroll
    for (int i = 0; i < TOPK; ++i)
        outi[(size_t)row * TOPK + i] = (float)idx[i];
}

// ---------------------------------------------------------------------------
extern "C" void kernel_launch(void* const* d_in, const int* in_sizes, int n_in,
                              void* d_out, int out_size, void* d_ws, size_t ws_size,
                              hipStream_t stream) {
    (void)in_sizes; (void)n_in; (void)out_size;
    const float* x = (const float*)d_in[0];
    const float* W = (const float*)d_in[1];
    const float* b = (const float*)d_in[2];

    float* outp = (float*)d_out;
    float* outi = outp + (size_t)M * E;

    const size_t wdt_bytes = sizeof(double) * (size_t)E * K;          // 2 MB
    const size_t wh_off    = wdt_bytes;
    const size_t wl_off    = wh_off + sizeof(short) * (size_t)E * K;  // +512 KB
    const size_t cnt_off   = wl_off + sizeof(short) * (size_t)E * K;  // +512 KB
    const size_t list_off  = cnt_off + 256;
    const size_t part_off  = list_off + (size_t)M * sizeof(int);
    const size_t need      = part_off + (size_t)SPLIT * M * E * sizeof(float);

    if (ws_size >= need) {
        double* WdT  = (double*)d_ws;
        short*  Whf  = (short*)((char*)d_ws + wh_off);
        short*  Wlf  = (short*)((char*)d_ws + wl_off);
        int*    cnt  = (int*)((char*)d_ws + cnt_off);
        int*    list = (int*)((char*)d_ws + list_off);
        float*  part = (float*)((char*)d_ws + part_off);

        prep_kernel<<<(E * K) / 256, 256, 0, stream>>>(W, Whf, Wlf, WdT, cnt);
        gate_kernel<<<(M / 64) * SPLIT, 256, 0, stream>>>(x, Whf, Wlf, part);
        reduce_kernel<<<M / 4, 256, 0, stream>>>(part, b, outp, outi, cnt, list);
        fix_kernel<<<1024, 512, 0, stream>>>(x, WdT, b, outp, outi, cnt, list);
    } else {
        fallback_kernel<<<M / 64, 64, 0, stream>>>(x, W, b, outp, outi);
    }
}

// Round 16
// 146.087 us; speedup vs baseline: 1.0626x; 1.0626x over previous
//
#include <hip/hip_runtime.h>
#include <cfloat>
#include <cmath>

#define M     16384
#define K     4096
#define E     64
#define TOPK  8
#define GAP_THRESH 1e-4f

#define SPLIT 4                 // K-split (gate)
#define KPS   (K / SPLIT)       // 1024 k per wave
#define NCH   (KPS / 32)        // 32 chunks of k32
#define FIXR  3                 // rows per fix block

typedef __attribute__((ext_vector_type(8))) short bf16x8;
typedef __attribute__((ext_vector_type(4))) float f32x4;

// ws layout: [WdT 2MB][Whf 512KB][Wlf 512KB][count 256B][list 64KB][part 16MB]

__device__ __forceinline__ short f2bf(float f) {           // RNE fp32->bf16
    unsigned u = __builtin_bit_cast(unsigned, f);
    u += 0x7FFFu + ((u >> 16) & 1u);
    return (short)(u >> 16);
}
__device__ __forceinline__ float bf2f(short h) {           // exact widen
    unsigned u = ((unsigned)(unsigned short)h) << 16;
    return __builtin_bit_cast(float, u);
}

// ---------------------------------------------------------------------------
// prep (proven r14/r15): Whf/Wlf in MFMA fragment order; WdT[k][e] fp64
// written coalesced; zero flag counter.
// ---------------------------------------------------------------------------
__global__ __launch_bounds__(256) void prep_kernel(const float* __restrict__ W,
                                                   short* __restrict__ Whf,
                                                   short* __restrict__ Wlf,
                                                   double* __restrict__ WdT,
                                                   int* __restrict__ count) {
    int t = blockIdx.x * 256 + threadIdx.x;   // t = e*4096 + k
    float w = W[t];
    short h = f2bf(w);
    short lo = f2bf(w - bf2f(h));
    int e = t >> 12, k = t & 4095;
    int gc = k >> 5, kk = k & 31;
    size_t fidx = (((size_t)gc * 4 + (e >> 4)) * 64 + (kk >> 3) * 16 + (e & 15)) * 8
                  + (kk & 7);
    Whf[fidx] = h;
    Wlf[fidx] = lo;
    // coalesced WdT write: reinterpret t as k-major (t = k2*64 + e2)
    int k2 = t >> 6, e2 = t & 63;
    WdT[t] = (double)W[(size_t)e2 * K + k2];
    if (t == 0) *count = 0;
}

// ---------------------------------------------------------------------------
// MFMA gate (proven r12-r15): LDS-free, explicit 2-deep register pipeline,
// fragment-ordered W, 16 waves/CU, no barriers.  x is L3-resident (256MB)
// so the 256MB stream runs at L3 BW -- near its floor, leave untouched.
// ---------------------------------------------------------------------------
struct XW {
    float4 xa, xb;
    bf16x8 h0, h1, h2, h3, l0, l1, l2, l3;
};

__device__ __forceinline__ void load_set(XW& s, const float* gx,
                                         const short* ph, const short* pl, int cc) {
    const int ko = cc * 32;
    s.xa = *reinterpret_cast<const float4*>(gx + ko);
    s.xb = *reinterpret_cast<const float4*>(gx + ko + 4);
    const short* bh = ph + (size_t)cc * 2048;
    const short* bl = pl + (size_t)cc * 2048;
    s.h0 = *reinterpret_cast<const bf16x8*>(bh);
    s.h1 = *reinterpret_cast<const bf16x8*>(bh + 512);
    s.h2 = *reinterpret_cast<const bf16x8*>(bh + 1024);
    s.h3 = *reinterpret_cast<const bf16x8*>(bh + 1536);
    s.l0 = *reinterpret_cast<const bf16x8*>(bl);
    s.l1 = *reinterpret_cast<const bf16x8*>(bl + 512);
    s.l2 = *reinterpret_cast<const bf16x8*>(bl + 1024);
    s.l3 = *reinterpret_cast<const bf16x8*>(bl + 1536);
}

__device__ __forceinline__ void compute_set(const XW& s, f32x4 acc[4]) {
    float vv[8] = {s.xa.x, s.xa.y, s.xa.z, s.xa.w, s.xb.x, s.xb.y, s.xb.z, s.xb.w};
    bf16x8 ah, al;
#pragma unroll
    for (int j = 0; j < 8; ++j) {
        short hh = f2bf(vv[j]);
        ah[j] = hh;
        al[j] = f2bf(vv[j] - bf2f(hh));
    }
    acc[0] = __builtin_amdgcn_mfma_f32_16x16x32_bf16(ah, s.h0, acc[0], 0, 0, 0);
    acc[0] = __builtin_amdgcn_mfma_f32_16x16x32_bf16(ah, s.l0, acc[0], 0, 0, 0);
    acc[0] = __builtin_amdgcn_mfma_f32_16x16x32_bf16(al, s.h0, acc[0], 0, 0, 0);
    acc[1] = __builtin_amdgcn_mfma_f32_16x16x32_bf16(ah, s.h1, acc[1], 0, 0, 0);
    acc[1] = __builtin_amdgcn_mfma_f32_16x16x32_bf16(ah, s.l1, acc[1], 0, 0, 0);
    acc[1] = __builtin_amdgcn_mfma_f32_16x16x32_bf16(al, s.h1, acc[1], 0, 0, 0);
    acc[2] = __builtin_amdgcn_mfma_f32_16x16x32_bf16(ah, s.h2, acc[2], 0, 0, 0);
    acc[2] = __builtin_amdgcn_mfma_f32_16x16x32_bf16(ah, s.l2, acc[2], 0, 0, 0);
    acc[2] = __builtin_amdgcn_mfma_f32_16x16x32_bf16(al, s.h2, acc[2], 0, 0, 0);
    acc[3] = __builtin_amdgcn_mfma_f32_16x16x32_bf16(ah, s.h3, acc[3], 0, 0, 0);
    acc[3] = __builtin_amdgcn_mfma_f32_16x16x32_bf16(ah, s.l3, acc[3], 0, 0, 0);
    acc[3] = __builtin_amdgcn_mfma_f32_16x16x32_bf16(al, s.h3, acc[3], 0, 0, 0);
}

__global__ __launch_bounds__(256) void gate_kernel(
    const float* __restrict__ x,
    const short* __restrict__ Whf,
    const short* __restrict__ Wlf,
    float* __restrict__ part)
{
    const int t  = threadIdx.x;
    const int l  = t & 63;
    const int wv = t >> 6;
    const int h    = blockIdx.x & (SPLIT - 1);        // 4 waves share k-slice
    const int row0 = (blockIdx.x >> 2) * 64 + wv * 16;
    const int k0   = h * KPS;

    const int kg   = l >> 4;                          // 0..3 k-granule
    const int xrow = row0 + (l & 15);

    const float* gx = x + (size_t)xrow * K + k0 + kg * 8;
    const short* ph = Whf + ((size_t)(k0 >> 5) * 4) * 512 + (size_t)l * 8;
    const short* pl = Wlf + ((size_t)(k0 >> 5) * 4) * 512 + (size_t)l * 8;

    f32x4 acc[4] = {{0,0,0,0},{0,0,0,0},{0,0,0,0},{0,0,0,0}};

    XW A, B;
    load_set(A, gx, ph, pl, 0);
    for (int c = 0; c < NCH; c += 2) {
        load_set(B, gx, ph, pl, c + 1);
        compute_set(A, acc);
        if (c + 2 < NCH) load_set(A, gx, ph, pl, c + 2);
        compute_set(B, acc);
    }

    // D layout (verified r10-r15): row = (l>>4)*4 + r, col = l&15
#pragma unroll
    for (int et = 0; et < 4; ++et)
#pragma unroll
        for (int r = 0; r < 4; ++r)
            part[((size_t)h * M + row0 + (l >> 4) * 4 + r) * E + et * 16 + (l & 15)]
                = acc[et][r];
}

// ---------------------------------------------------------------------------
// Reduce + top-9 + sparse softmax + ambiguity flag (proven rounds 3-15).
// ---------------------------------------------------------------------------
__global__ __launch_bounds__(256) void reduce_kernel(
    const float* __restrict__ part,
    const float* __restrict__ b,
    float* __restrict__ outp,
    float* __restrict__ outi,
    int*   __restrict__ count,
    int*   __restrict__ list)
{
    const int lane = threadIdx.x & 63;
    const int w    = threadIdx.x >> 6;
    const int row  = blockIdx.x * 4 + w;

    float orig = b[lane];
#pragma unroll
    for (int hh = 0; hh < SPLIT; ++hh)
        orig += part[((size_t)hh * M + row) * E + lane];

    float cur = orig;
    float vals[9];
    float myidxf = 0.0f;
    bool  sel = false;

#pragma unroll
    for (int i = 0; i < 9; ++i) {
        float m = cur;
#pragma unroll
        for (int off = 32; off > 0; off >>= 1)
            m = fmaxf(m, __shfl_xor(m, off, 64));
        unsigned long long msk = __ballot(cur == m);
        int il = __ffsll((long long)msk) - 1;
        vals[i] = m;
        if (lane == il) { cur = -FLT_MAX; if (i < TOPK) sel = true; }
        if (i < TOPK && lane == i) myidxf = (float)il;
    }

    float ssum = 0.0f;
#pragma unroll
    for (int i = 0; i < TOPK; ++i) ssum += expf(vals[i] - vals[0]);
    float p = sel ? (expf(orig - vals[0]) / ssum) : 0.0f;

    outp[(size_t)row * E + lane] = p;
    if (lane < TOPK) outi[(size_t)row * TOPK + lane] = myidxf;

    float mingap = FLT_MAX;
#pragma unroll
    for (int i = 0; i < 8; ++i) mingap = fminf(mingap, vals[i] - vals[i + 1]);
    if (lane == 0 && mingap < GAP_THRESH) {
        int pos = atomicAdd(count, 1);
        if (pos < M) list[pos] = row;
    }
}

// ---------------------------------------------------------------------------
// fp64 rescue, r16: the rescue is BW-bound on WdT re-reads (cnt/FIXR blocks
// x 2MB each; r12-r15 all fit traffic/BW, not latency).  Two traffic cuts:
// GAP_THRESH 3e-4 -> 1e-4 (cnt ~390 -> ~130; still >=7 sigma safe) and
// FIXR 2 -> 3 (each WdT load shared by 3 rows).  Inner loop keeps r14's
// proven rotation (r15's 32-load burst throttled the miss queues: -9us).
// 512 thr = 8 waves x 512 k; waves 0-2 run the proven ballot epilogues.
// ---------------------------------------------------------------------------
__global__ __launch_bounds__(512) void fix_kernel(
    const float*  __restrict__ x,
    const double* __restrict__ WdT,
    const float*  __restrict__ b,
    float* __restrict__ outp,
    float* __restrict__ outi,
    const int* __restrict__ count,
    const int* __restrict__ list)
{
    __shared__ float  xs[FIXR][K];           // 48 KB
    __shared__ double psum[8][FIXR][E];      // 12 KB
    const int t   = threadIdx.x;
    const int l   = t & 63;
    const int wv  = t >> 6;                  // 0..7
    const int cnt = *count;

    for (int base = blockIdx.x * FIXR; base < cnt; base += gridDim.x * FIXR) {
        int row[FIXR];
#pragma unroll
        for (int r = 0; r < FIXR; ++r)
            row[r] = list[min(base + r, cnt - 1)];

        // stage rows: 3072 float4 over 512 thr = 6 each, coalesced
#pragma unroll
        for (int j = 0; j < 6; ++j) {
            const int i4 = j * 512 + t;           // 0..3071
            const int rr = i4 >> 10;              // row 0..2
            const int p4 = i4 & 1023;
            reinterpret_cast<float4*>(xs[rr])[p4] =
                reinterpret_cast<const float4*>(x + (size_t)row[rr] * K)[p4];
        }
        __syncthreads();

        const int k0 = wv << 9;                   // 512 k per wave
        const double* wp = WdT + (size_t)k0 * E + l;

        double a00 = 0.0, a01 = 0.0, a02 = 0.0, a03 = 0.0;
        double a10 = 0.0, a11 = 0.0, a12 = 0.0, a13 = 0.0;
        double a20 = 0.0, a21 = 0.0, a22 = 0.0, a23 = 0.0;

        double c0 = wp[0], c1 = wp[E], c2 = wp[2 * E], c3 = wp[3 * E];
        for (int kk = 0; kk < 512; kk += 4) {
            // unconditional 1-deep prefetch (over-read lands in Whf, valid ws)
            const double* np = wp + (size_t)(kk + 4) * E;
            double n0 = np[0], n1 = np[E], n2 = np[2 * E], n3 = np[3 * E];
            float4 xv0 = *reinterpret_cast<const float4*>(xs[0] + k0 + kk);
            float4 xv1 = *reinterpret_cast<const float4*>(xs[1] + k0 + kk);
            float4 xv2 = *reinterpret_cast<const float4*>(xs[2] + k0 + kk);
            a00 = fma((double)xv0.x, c0, a00);
            a01 = fma((double)xv0.y, c1, a01);
            a02 = fma((double)xv0.z, c2, a02);
            a03 = fma((double)xv0.w, c3, a03);
            a10 = fma((double)xv1.x, c0, a10);
            a11 = fma((double)xv1.y, c1, a11);
            a12 = fma((double)xv1.z, c2, a12);
            a13 = fma((double)xv1.w, c3, a13);
            a20 = fma((double)xv2.x, c0, a20);
            a21 = fma((double)xv2.y, c1, a21);
            a22 = fma((double)xv2.z, c2, a22);
            a23 = fma((double)xv2.w, c3, a23);
            c0 = n0; c1 = n1; c2 = n2; c3 = n3;
        }
        psum[wv][0][l] = (a00 + a01) + (a02 + a03);
        psum[wv][1][l] = (a10 + a11) + (a12 + a13);
        psum[wv][2][l] = (a20 + a21) + (a22 + a23);
        __syncthreads();

        if (wv < FIXR) {
            const int r   = wv;
            const int idx = base + r;
            double orig = (double)b[l];
#pragma unroll
            for (int w = 0; w < 8; ++w) orig += psum[w][r][l];
            double cur = orig;

            double vals[TOPK];
            float  myidxf = 0.0f;
            bool   sel = false;

#pragma unroll
            for (int tt = 0; tt < TOPK; ++tt) {
                double m = cur;
#pragma unroll
                for (int off = 32; off > 0; off >>= 1) {
                    double o = __shfl_xor(m, off, 64);
                    m = fmax(m, o);
                }
                unsigned long long msk = __ballot(cur == m);
                int il = __ffsll((long long)msk) - 1;
                vals[tt] = m;
                if (l == il) { cur = -DBL_MAX; sel = true; }
                if (l == tt)  myidxf = (float)il;
            }

            double ssum = 0.0;
#pragma unroll
            for (int tt = 0; tt < TOPK; ++tt) ssum += exp(vals[tt] - vals[0]);
            float p = sel ? (float)(exp(orig - vals[0]) / ssum) : 0.0f;

            if (idx < cnt) {
                const int rw = row[r];
                outp[(size_t)rw * E + l] = p;
                if (l < TOPK) outi[(size_t)rw * TOPK + l] = myidxf;
            }
        }
        __syncthreads();   // xs/psum reused next pass
    }
}

// ---------------------------------------------------------------------------
// Fallback (tiny ws): per-thread-row full fp64 from f32 W.  Correct, slow.
// ---------------------------------------------------------------------------
__global__ __launch_bounds__(64) void fallback_kernel(
    const float* __restrict__ x,
    const float* __restrict__ W,
    const float* __restrict__ b,
    float* __restrict__ outp,
    float* __restrict__ outi)
{
    const int row = blockIdx.x * 64 + threadIdx.x;
    double lg[64];
#pragma unroll
    for (int e = 0; e < 64; ++e) lg[e] = (double)b[e];
    const float* xr = x + (size_t)row * K;
    for (int k = 0; k < K; k += 4) {
        float4 xa = *reinterpret_cast<const float4*>(xr + k);
        double xd[4] = {(double)xa.x, (double)xa.y, (double)xa.z, (double)xa.w};
#pragma unroll
        for (int e = 0; e < 64; ++e) {
            const float* wp = W + (size_t)e * K + k;
            double a = lg[e];
#pragma unroll
            for (int j = 0; j < 4; ++j) a = fma(xd[j], (double)wp[j], a);
            lg[e] = a;
        }
    }
    unsigned long long selm = 0ull;
    double vals[TOPK]; int idx[TOPK];
#pragma unroll
    for (int i = 0; i < TOPK; ++i) {
        double m = -DBL_MAX; int mi = 0;
#pragma unroll
        for (int e = 0; e < 64; ++e) {
            bool gt = !((selm >> e) & 1ull) && (lg[e] > m);
            m = gt ? lg[e] : m; mi = gt ? e : mi;
        }
        vals[i] = m; idx[i] = mi; selm |= (1ull << mi);
    }
    double ssum = 0.0;
#pragma unroll
    for (int i = 0; i < TOPK; ++i) ssum += exp(vals[i] - vals[0]);
    double inv = 1.0 / ssum;
#pragma unroll
    for (int e = 0; e < 64; ++e)
        outp[(size_t)row * E + e] =
            ((selm >> e) & 1ull) ? (float)(exp(lg[e] - vals[0]) * inv) : 0.0f;
#pragma unroll
    for (int i = 0; i < TOPK; ++i)
        outi[(size_t)row * TOPK + i] = (float)idx[i];
}

// ---------------------------------------------------------------------------
extern "C" void kernel_launch(void* const* d_in, const int* in_sizes, int n_in,
                              void* d_out, int out_size, void* d_ws, size_t ws_size,
                              hipStream_t stream) {
    (void)in_sizes; (void)n_in; (void)out_size;
    const float* x = (const float*)d_in[0];
    const float* W = (const float*)d_in[1];
    const float* b = (const float*)d_in[2];

    float* outp = (float*)d_out;
    float* outi = outp + (size_t)M * E;

    const size_t wdt_bytes = sizeof(double) * (size_t)E * K;          // 2 MB
    const size_t wh_off    = wdt_bytes;
    const size_t wl_off    = wh_off + sizeof(short) * (size_t)E * K;  // +512 KB
    const size_t cnt_off   = wl_off + sizeof(short) * (size_t)E * K;  // +512 KB
    const size_t list_off  = cnt_off + 256;
    const size_t part_off  = list_off + (size_t)M * sizeof(int);
    const size_t need      = part_off + (size_t)SPLIT * M * E * sizeof(float);

    if (ws_size >= need) {
        double* WdT  = (double*)d_ws;
        short*  Whf  = (short*)((char*)d_ws + wh_off);
        short*  Wlf  = (short*)((char*)d_ws + wl_off);
        int*    cnt  = (int*)((char*)d_ws + cnt_off);
        int*    list = (int*)((char*)d_ws + list_off);
        float*  part = (float*)((char*)d_ws + part_off);

        prep_kernel<<<(E * K) / 256, 256, 0, stream>>>(W, Whf, Wlf, WdT, cnt);
        gate_kernel<<<(M / 64) * SPLIT, 256, 0, stream>>>(x, Whf, Wlf, part);
        reduce_kernel<<<M / 4, 256, 0, stream>>>(part, b, outp, outi, cnt, list);
        fix_kernel<<<1024, 512, 0, stream>>>(x, WdT, b, outp, outi, cnt, list);
    } else {
        fallback_kernel<<<M / 64, 64, 0, stream>>>(x, W, b, outp, outi);
    }
}

// Round 17
// 128.694 us; speedup vs baseline: 1.2063x; 1.1352x over previous
//
#include <hip/hip_runtime.h>
#include <cfloat>
#include <cmath>

#define M     16384
#define K     4096
#define E     64
#define TOPK  8
#define GAP_THRESH 1e-4f

#define SPLIT 4                 // K-split (gate)
#define KPS   (K / SPLIT)       // 1024 k per wave
#define NCH   (KPS / 32)        // 32 chunks of k32

typedef __attribute__((ext_vector_type(8))) short bf16x8;
typedef __attribute__((ext_vector_type(4))) float f32x4;

// ws layout: [Whf 512KB][Wlf 512KB][count 256B][list 64KB][part 16MB]

__device__ __forceinline__ short f2bf(float f) {           // RNE fp32->bf16
    unsigned u = __builtin_bit_cast(unsigned, f);
    u += 0x7FFFu + ((u >> 16) & 1u);
    return (short)(u >> 16);
}
__device__ __forceinline__ float bf2f(short h) {           // exact widen
    unsigned u = ((unsigned)(unsigned short)h) << 16;
    return __builtin_bit_cast(float, u);
}

// ---------------------------------------------------------------------------
// prep: Whf/Wlf in MFMA fragment order (proven r12-r16); zero flag counter.
// (WdT eliminated -- fix now reads f32 W directly.)
// ---------------------------------------------------------------------------
__global__ __launch_bounds__(256) void prep_kernel(const float* __restrict__ W,
                                                   short* __restrict__ Whf,
                                                   short* __restrict__ Wlf,
                                                   int* __restrict__ count) {
    int t = blockIdx.x * 256 + threadIdx.x;   // t = e*4096 + k
    float w = W[t];
    short h = f2bf(w);
    short lo = f2bf(w - bf2f(h));
    int e = t >> 12, k = t & 4095;
    int gc = k >> 5, kk = k & 31;
    size_t fidx = (((size_t)gc * 4 + (e >> 4)) * 64 + (kk >> 3) * 16 + (e & 15)) * 8
                  + (kk & 7);
    Whf[fidx] = h;
    Wlf[fidx] = lo;
    if (t == 0) *count = 0;
}

// ---------------------------------------------------------------------------
// MFMA gate (proven r12-r16): LDS-free, explicit 2-deep register pipeline,
// fragment-ordered W, 16 waves/CU, no barriers.
// ---------------------------------------------------------------------------
struct XW {
    float4 xa, xb;
    bf16x8 h0, h1, h2, h3, l0, l1, l2, l3;
};

__device__ __forceinline__ void load_set(XW& s, const float* gx,
                                         const short* ph, const short* pl, int cc) {
    const int ko = cc * 32;
    s.xa = *reinterpret_cast<const float4*>(gx + ko);
    s.xb = *reinterpret_cast<const float4*>(gx + ko + 4);
    const short* bh = ph + (size_t)cc * 2048;
    const short* bl = pl + (size_t)cc * 2048;
    s.h0 = *reinterpret_cast<const bf16x8*>(bh);
    s.h1 = *reinterpret_cast<const bf16x8*>(bh + 512);
    s.h2 = *reinterpret_cast<const bf16x8*>(bh + 1024);
    s.h3 = *reinterpret_cast<const bf16x8*>(bh + 1536);
    s.l0 = *reinterpret_cast<const bf16x8*>(bl);
    s.l1 = *reinterpret_cast<const bf16x8*>(bl + 512);
    s.l2 = *reinterpret_cast<const bf16x8*>(bl + 1024);
    s.l3 = *reinterpret_cast<const bf16x8*>(bl + 1536);
}

__device__ __forceinline__ void compute_set(const XW& s, f32x4 acc[4]) {
    float vv[8] = {s.xa.x, s.xa.y, s.xa.z, s.xa.w, s.xb.x, s.xb.y, s.xb.z, s.xb.w};
    bf16x8 ah, al;
#pragma unroll
    for (int j = 0; j < 8; ++j) {
        short hh = f2bf(vv[j]);
        ah[j] = hh;
        al[j] = f2bf(vv[j] - bf2f(hh));
    }
    acc[0] = __builtin_amdgcn_mfma_f32_16x16x32_bf16(ah, s.h0, acc[0], 0, 0, 0);
    acc[0] = __builtin_amdgcn_mfma_f32_16x16x32_bf16(ah, s.l0, acc[0], 0, 0, 0);
    acc[0] = __builtin_amdgcn_mfma_f32_16x16x32_bf16(al, s.h0, acc[0], 0, 0, 0);
    acc[1] = __builtin_amdgcn_mfma_f32_16x16x32_bf16(ah, s.h1, acc[1], 0, 0, 0);
    acc[1] = __builtin_amdgcn_mfma_f32_16x16x32_bf16(ah, s.l1, acc[1], 0, 0, 0);
    acc[1] = __builtin_amdgcn_mfma_f32_16x16x32_bf16(al, s.h1, acc[1], 0, 0, 0);
    acc[2] = __builtin_amdgcn_mfma_f32_16x16x32_bf16(ah, s.h2, acc[2], 0, 0, 0);
    acc[2] = __builtin_amdgcn_mfma_f32_16x16x32_bf16(ah, s.l2, acc[2], 0, 0, 0);
    acc[2] = __builtin_amdgcn_mfma_f32_16x16x32_bf16(al, s.h2, acc[2], 0, 0, 0);
    acc[3] = __builtin_amdgcn_mfma_f32_16x16x32_bf16(ah, s.h3, acc[3], 0, 0, 0);
    acc[3] = __builtin_amdgcn_mfma_f32_16x16x32_bf16(ah, s.l3, acc[3], 0, 0, 0);
    acc[3] = __builtin_amdgcn_mfma_f32_16x16x32_bf16(al, s.h3, acc[3], 0, 0, 0);
}

__global__ __launch_bounds__(256) void gate_kernel(
    const float* __restrict__ x,
    const short* __restrict__ Whf,
    const short* __restrict__ Wlf,
    float* __restrict__ part)
{
    const int t  = threadIdx.x;
    const int l  = t & 63;
    const int wv = t >> 6;
    const int h    = blockIdx.x & (SPLIT - 1);        // 4 waves share k-slice
    const int row0 = (blockIdx.x >> 2) * 64 + wv * 16;
    const int k0   = h * KPS;

    const int kg   = l >> 4;                          // 0..3 k-granule
    const int xrow = row0 + (l & 15);

    const float* gx = x + (size_t)xrow * K + k0 + kg * 8;
    const short* ph = Whf + ((size_t)(k0 >> 5) * 4) * 512 + (size_t)l * 8;
    const short* pl = Wlf + ((size_t)(k0 >> 5) * 4) * 512 + (size_t)l * 8;

    f32x4 acc[4] = {{0,0,0,0},{0,0,0,0},{0,0,0,0},{0,0,0,0}};

    XW A, B;
    load_set(A, gx, ph, pl, 0);
    for (int c = 0; c < NCH; c += 2) {
        load_set(B, gx, ph, pl, c + 1);
        compute_set(A, acc);
        if (c + 2 < NCH) load_set(A, gx, ph, pl, c + 2);
        compute_set(B, acc);
    }

    // D layout (verified r10-r16): row = (l>>4)*4 + r, col = l&15
#pragma unroll
    for (int et = 0; et < 4; ++et)
#pragma unroll
        for (int r = 0; r < 4; ++r)
            part[((size_t)h * M + row0 + (l >> 4) * 4 + r) * E + et * 16 + (l & 15)]
                = acc[et][r];
}

// ---------------------------------------------------------------------------
// Reduce + top-9 + sparse softmax + ambiguity flag (proven rounds 3-16).
// ---------------------------------------------------------------------------
__global__ __launch_bounds__(256) void reduce_kernel(
    const float* __restrict__ part,
    const float* __restrict__ b,
    float* __restrict__ outp,
    float* __restrict__ outi,
    int*   __restrict__ count,
    int*   __restrict__ list)
{
    const int lane = threadIdx.x & 63;
    const int w    = threadIdx.x >> 6;
    const int row  = blockIdx.x * 4 + w;

    float orig = b[lane];
#pragma unroll
    for (int hh = 0; hh < SPLIT; ++hh)
        orig += part[((size_t)hh * M + row) * E + lane];

    float cur = orig;
    float vals[9];
    float myidxf = 0.0f;
    bool  sel = false;

#pragma unroll
    for (int i = 0; i < 9; ++i) {
        float m = cur;
#pragma unroll
        for (int off = 32; off > 0; off >>= 1)
            m = fmaxf(m, __shfl_xor(m, off, 64));
        unsigned long long msk = __ballot(cur == m);
        int il = __ffsll((long long)msk) - 1;
        vals[i] = m;
        if (lane == il) { cur = -FLT_MAX; if (i < TOPK) sel = true; }
        if (i < TOPK && lane == i) myidxf = (float)il;
    }

    float ssum = 0.0f;
#pragma unroll
    for (int i = 0; i < TOPK; ++i) ssum += expf(vals[i] - vals[0]);
    float p = sel ? (expf(orig - vals[0]) / ssum) : 0.0f;

    outp[(size_t)row * E + lane] = p;
    if (lane < TOPK) outi[(size_t)row * TOPK + lane] = myidxf;

    float mingap = FLT_MAX;
#pragma unroll
    for (int i = 0; i < 8; ++i) mingap = fminf(mingap, vals[i] - vals[i + 1]);
    if (lane == 0 && mingap < GAP_THRESH) {
        int pos = atomicAdd(count, 1);
        if (pos < M) list[pos] = row;
    }
}

// ---------------------------------------------------------------------------
// fp64 rescue, r17: per-block LOAD-PARALLEL redesign.  r12-r16 were
// per-block-latency-bound (4 rotating 512B loads in flight -> ~5 B/cyc/wave;
// cnt-invariant ~100us).  Now: one row per block, 512 thr; wave wv owns
// experts wv*8..+7 with lane-parallel k: per j-step, 1 LDS float4 of x +
// 8 INDEPENDENT coalesced 1KB wave-loads of f32 W (8 streams in flight) +
// 32 fp64 FMAs.  W read as f32 (1MB, L2-resident; fp64 upcast per-FMA ==
// numpy float64 math on the same values).  Butterfly fp64 reduce -> LDS ->
// wave 0 runs the proven ballot epilogue.  cnt <= 1024 -> one pass.
// ---------------------------------------------------------------------------
__global__ __launch_bounds__(512) void fix_kernel(
    const float* __restrict__ x,
    const float* __restrict__ W,
    const float* __restrict__ b,
    float* __restrict__ outp,
    float* __restrict__ outi,
    const int* __restrict__ count,
    const int* __restrict__ list)
{
    __shared__ float  xs[K];         // 16 KB
    __shared__ double lsum[E];       // 512 B
    const int t   = threadIdx.x;
    const int l   = t & 63;
    const int wv  = t >> 6;          // 0..7
    const int cnt = *count;

    for (int i = blockIdx.x; i < cnt; i += gridDim.x) {
        const int row = list[i];

        // stage x row: 1024 float4 over 512 thr = 2 each, coalesced
        const float4* xr4 = reinterpret_cast<const float4*>(x + (size_t)row * K);
        reinterpret_cast<float4*>(xs)[t]       = xr4[t];
        reinterpret_cast<float4*>(xs)[512 + t] = xr4[512 + t];
        __syncthreads();

        const int e0 = wv * 8;
        double acc[8] = {};              // static-indexed via full unroll
#pragma unroll 4
        for (int j = 0; j < 16; ++j) {   // k = 4l + 256j
            float4 xv = reinterpret_cast<const float4*>(xs)[l + 64 * j];
#pragma unroll
            for (int e8 = 0; e8 < 8; ++e8) {
                float4 wv4 = reinterpret_cast<const float4*>(
                    W + (size_t)(e0 + e8) * K)[l + 64 * j];
                acc[e8] = fma((double)xv.x, (double)wv4.x, acc[e8]);
                acc[e8] = fma((double)xv.y, (double)wv4.y, acc[e8]);
                acc[e8] = fma((double)xv.z, (double)wv4.z, acc[e8]);
                acc[e8] = fma((double)xv.w, (double)wv4.w, acc[e8]);
            }
        }

        // fp64 butterfly reduce per expert; all lanes end with the sum
#pragma unroll
        for (int e8 = 0; e8 < 8; ++e8) {
            double v = acc[e8];
#pragma unroll
            for (int off = 32; off > 0; off >>= 1)
                v += __shfl_xor(v, off, 64);
            if (l == e8) lsum[e0 + e8] = v;
        }
        __syncthreads();

        if (wv == 0) {
            const double orig = lsum[l] + (double)b[l];
            double cur = orig;

            double vals[TOPK];
            float  myidxf = 0.0f;
            bool   sel = false;

#pragma unroll
            for (int tt = 0; tt < TOPK; ++tt) {
                double m = cur;
#pragma unroll
                for (int off = 32; off > 0; off >>= 1) {
                    double o = __shfl_xor(m, off, 64);
                    m = fmax(m, o);
                }
                unsigned long long msk = __ballot(cur == m);
                int il = __ffsll((long long)msk) - 1;
                vals[tt] = m;
                if (l == il) { cur = -DBL_MAX; sel = true; }
                if (l == tt)  myidxf = (float)il;
            }

            double ssum = 0.0;
#pragma unroll
            for (int tt = 0; tt < TOPK; ++tt) ssum += exp(vals[tt] - vals[0]);
            float p = sel ? (float)(exp(orig - vals[0]) / ssum) : 0.0f;

            outp[(size_t)row * E + l] = p;
            if (l < TOPK) outi[(size_t)row * TOPK + l] = myidxf;
        }
        __syncthreads();   // xs/lsum reused next pass
    }
}

// ---------------------------------------------------------------------------
// Fallback (tiny ws): per-thread-row full fp64 from f32 W.  Correct, slow.
// ---------------------------------------------------------------------------
__global__ __launch_bounds__(64) void fallback_kernel(
    const float* __restrict__ x,
    const float* __restrict__ W,
    const float* __restrict__ b,
    float* __restrict__ outp,
    float* __restrict__ outi)
{
    const int row = blockIdx.x * 64 + threadIdx.x;
    double lg[64];
#pragma unroll
    for (int e = 0; e < 64; ++e) lg[e] = (double)b[e];
    const float* xr = x + (size_t)row * K;
    for (int k = 0; k < K; k += 4) {
        float4 xa = *reinterpret_cast<const float4*>(xr + k);
        double xd[4] = {(double)xa.x, (double)xa.y, (double)xa.z, (double)xa.w};
#pragma unroll
        for (int e = 0; e < 64; ++e) {
            const float* wp = W + (size_t)e * K + k;
            double a = lg[e];
#pragma unroll
            for (int j = 0; j < 4; ++j) a = fma(xd[j], (double)wp[j], a);
            lg[e] = a;
        }
    }
    unsigned long long selm = 0ull;
    double vals[TOPK]; int idx[TOPK];
#pragma unroll
    for (int i = 0; i < TOPK; ++i) {
        double m = -DBL_MAX; int mi = 0;
#pragma unroll
        for (int e = 0; e < 64; ++e) {
            bool gt = !((selm >> e) & 1ull) && (lg[e] > m);
            m = gt ? lg[e] : m; mi = gt ? e : mi;
        }
        vals[i] = m; idx[i] = mi; selm |= (1ull << mi);
    }
    double ssum = 0.0;
#pragma unroll
    for (int i = 0; i < TOPK; ++i) ssum += exp(vals[i] - vals[0]);
    double inv = 1.0 / ssum;
#pragma unroll
    for (int e = 0; e < 64; ++e)
        outp[(size_t)row * E + e] =
            ((selm >> e) & 1ull) ? (float)(exp(lg[e] - vals[0]) * inv) : 0.0f;
#pragma unroll
    for (int i = 0; i < TOPK; ++i)
        outi[(size_t)row * TOPK + i] = (float)idx[i];
}

// ---------------------------------------------------------------------------
extern "C" void kernel_launch(void* const* d_in, const int* in_sizes, int n_in,
                              void* d_out, int out_size, void* d_ws, size_t ws_size,
                              hipStream_t stream) {
    (void)in_sizes; (void)n_in; (void)out_size;
    const float* x = (const float*)d_in[0];
    const float* W = (const float*)d_in[1];
    const float* b = (const float*)d_in[2];

    float* outp = (float*)d_out;
    float* outi = outp + (size_t)M * E;

    const size_t wh_off   = 0;
    const size_t wl_off   = wh_off + sizeof(short) * (size_t)E * K;   // +512 KB
    const size_t cnt_off  = wl_off + sizeof(short) * (size_t)E * K;   // +512 KB
    const size_t list_off = cnt_off + 256;
    const size_t part_off = list_off + (size_t)M * sizeof(int);
    const size_t need     = part_off + (size_t)SPLIT * M * E * sizeof(float);

    if (ws_size >= need) {
        short*  Whf  = (short*)((char*)d_ws + wh_off);
        short*  Wlf  = (short*)((char*)d_ws + wl_off);
        int*    cnt  = (int*)((char*)d_ws + cnt_off);
        int*    list = (int*)((char*)d_ws + list_off);
        float*  part = (float*)((char*)d_ws + part_off);

        prep_kernel<<<(E * K) / 256, 256, 0, stream>>>(W, Whf, Wlf, cnt);
        gate_kernel<<<(M / 64) * SPLIT, 256, 0, stream>>>(x, Whf, Wlf, part);
        reduce_kernel<<<M / 4, 256, 0, stream>>>(part, b, outp, outi, cnt, list);
        fix_kernel<<<1024, 512, 0, stream>>>(x, W, b, outp, outi, cnt, list);
    } else {
        fallback_kernel<<<M / 64, 64, 0, stream>>>(x, W, b, outp, outi);
    }
}